// Round 4
// baseline (448.063 us; speedup 1.0000x reference)
//
#include <hip/hip_runtime.h>
#include <hip/hip_bf16.h>
#include <cstdint>

// ---------------------------------------------------------------------------
// WindowAttention, fully fused, static-LDS 38.9KB: B windows (2048), N=64,
// DIM=192, H=6 heads, d=32.
//   prep : weights -> bf16 MFMA-fragment-linear, comb = rel_bias + mask
//   fused: per-window block (512 thr, 8 waves). 3 passes over head-pairs:
//            pass p: QKV GEMM (A-frags in regs, B-frags from L2) for heads
//            {2p,2p+1} -> Q,K,V^T in LDS -> attention (1 task/wave, softmax
//            in regs) -> Xa slice in LDS -> rank-64 proj update into reg acc.
//          After 3 passes: write out fp32 + bias.
// LDS live-range overlays (the round-4 lever):
//   * lq2/lk2/lvt2/lxa alias the dead X-staging buffer (af hoisted to regs)
//   * P-scratch aliases lq2+lk2, legalized by a barrier after the QK^T MFMAs
// -> 38912 B/block (was 64512) -> 3-4 blocks/CU instead of 2.
// __launch_bounds__(512,6) pins VGPR<=85 (measured need: 84) for 24 waves/CU.
// ---------------------------------------------------------------------------

#define NTOK 64
#define NH 6
#define HD 32
#define WDIM 192
#define SCALE 0.17677669529663689f

typedef __bf16 bf16x8 __attribute__((ext_vector_type(8)));
typedef float f32x4 __attribute__((ext_vector_type(4)));

__device__ inline unsigned short f2bf(float f) {
    union { float f; unsigned u; } v; v.f = f;
    unsigned r = v.u + 0x7fff + ((v.u >> 16) & 1);   // RNE
    return (unsigned short)(r >> 16);
}

// ---------------------------------------------------------------------------
// K0: weight cast into MFMA B-fragment-linear order + combined bias table.
// Wfrag[((ntile*6 + ks)*64 + lane)*8 + j] = W[k][n], n = ntile*16+(lane&15),
// k = ks*32+(lane>>4)*8+j  -> a wave's B-fragment is one coalesced 1KB read.
// comb[w][h][r][c] = rpbt[relidx(r,c)][h] + mask[w][r][c]  (64*6*64*64 fp32)
// ---------------------------------------------------------------------------
__global__ __launch_bounds__(256) void prep_kernel(
    const float* __restrict__ w_qkv, const float* __restrict__ w_proj,
    const float* __restrict__ rpbt, const float* __restrict__ mask,
    unsigned short* __restrict__ wqkv_f, unsigned short* __restrict__ wproj_f,
    float* __restrict__ comb) {
    int idx = blockIdx.x * 256 + threadIdx.x;
    if (idx < 576 * 192) {
        int j = idx & 7, lane = (idx >> 3) & 63, t = idx >> 9;   // t = 0..215
        int ks = t % 6, ntile = t / 6;                           // ntile 0..35
        int n = ntile * 16 + (lane & 15);                        // 0..575
        int k = ks * 32 + (lane >> 4) * 8 + j;                   // 0..191
        wqkv_f[idx] = f2bf(w_qkv[k * 576 + n]);
        return;
    }
    int i2 = idx - 576 * 192;
    if (i2 < 192 * 192) {
        int j = i2 & 7, lane = (i2 >> 3) & 63, t = i2 >> 9;      // t = 0..71
        int ks = t % 6, ntile = t / 6;                           // ntile 0..11
        int n = ntile * 16 + (lane & 15);                        // 0..191
        int k = ks * 32 + (lane >> 4) * 8 + j;                   // 0..191
        wproj_f[i2] = f2bf(w_proj[k * 192 + n]);
        return;
    }
    int i3 = i2 - 192 * 192;
    if (i3 < 64 * NH * NTOK * NTOK) {
        int c = i3 & 63, r = (i3 >> 6) & 63;
        int h = (i3 >> 12) % NH;
        int w = i3 / (NH * 4096);
        int rr = (r >> 3) - (c >> 3) + 7;     // row-coord delta (0..14)
        int cc = (r & 7) - (c & 7) + 7;       // col-coord delta (0..14)
        comb[i3] = rpbt[(rr * 15 + cc) * NH + h] + mask[w * 4096 + r * 64 + c];
    }
}

// ---------------------------------------------------------------------------
// Fused per-window kernel. 512 threads = 8 waves: wm = wave>>2 (row half),
// wn = wave&3 (n-group). Static LDS: sm[19456] shorts = 38912 B.
//   phase 0 : lx  = sm[0..12800)            X bf16 [64][200]
//   overlay : lq2 = sm[0..5120)             Q pair [2][64][40]
//             lk2 = sm[5120..10240)         K pair [2][64][40]
//             lvt2= sm[10240..14848)        V^T    [2][32][72]
//             lxa = sm[14848..19456)        Xa slice [64][72]
//             lsp = sm[wave*1152..+1152)    P scratch (aliases lq2/lk2,
//                                           valid after barrier B3)
// Barriers/pass: B1 (pre-epilogue), B2 (post-epilogue), B3 (post-QK^T,
// legalizes lsp overlay), B4 (pre-proj, lxa cross-wave).
// ---------------------------------------------------------------------------
__global__ __launch_bounds__(512, 6) void fused_kernel(
    const float* __restrict__ X, const unsigned short* __restrict__ Wqf,
    const float* __restrict__ b_qkv, const unsigned short* __restrict__ Wpf,
    const float* __restrict__ b_proj, const float* __restrict__ comb,
    float* __restrict__ out) {
    __shared__ unsigned short sm[19456];
    unsigned short* lx   = sm;              // [64][200], dies at af-hoist
    unsigned short* lq2  = sm;              // [2][64][40]
    unsigned short* lk2  = sm + 5120;       // [2][64][40]
    unsigned short* lvt2 = sm + 10240;      // [2][32][72]
    unsigned short* lxa  = sm + 14848;      // [64][72]

    const int tid = threadIdx.x;
    const int bwin = blockIdx.x;
    const int wave = tid >> 6, lane = tid & 63;
    const int l15 = lane & 15, quad = lane >> 4;
    const int wm = wave >> 2, wn = wave & 3;

    // ---- stage X (64x192 fp32 -> bf16) ----
    const float4* xg = (const float4*)(X + (size_t)bwin * 64 * 192);
    for (int i = 0; i < 6; i++) {
        int e4 = tid + i * 512;            // 3072 float4
        int row = e4 / 48, c4 = e4 % 48;
        float4 v = xg[e4];
        union { unsigned short s[4]; uint2 u; } pk;
        pk.s[0] = f2bf(v.x); pk.s[1] = f2bf(v.y);
        pk.s[2] = f2bf(v.z); pk.s[3] = f2bf(v.w);
        *(uint2*)&lx[row * 200 + c4 * 4] = pk.u;
    }
    __syncthreads();

    // ---- hoist A-fragments (X rows wm*32..+32, all K) into registers ----
    bf16x8 af[2][6];
    for (int mt = 0; mt < 2; mt++)
        for (int ks = 0; ks < 6; ks++)
            af[mt][ks] = *(const bf16x8*)&lx[(wm * 32 + mt * 16 + l15) * 200 + ks * 32 + quad * 8];
    // lx dead from here (overlay becomes writable after B1 of pass 0)
    unsigned short* lspw = sm + wave * 1152;   // [16][72] per wave

    f32x4 pacc[2][3];                           // proj accumulator, all passes
    for (int mt = 0; mt < 2; mt++)
        for (int nt = 0; nt < 3; nt++)
            pacc[mt][nt] = (f32x4){0.f, 0.f, 0.f, 0.f};

    const float* combg = comb + ((size_t)(bwin & 63) * NH) * 4096;

    for (int p = 0; p < 3; p++) {
        // ---- QKV GEMM for head-pair p (regs + global only, no LDS) ----
        f32x4 acc[2][3];
        for (int mt = 0; mt < 2; mt++)
            for (int i = 0; i < 3; i++)
                acc[mt][i] = (f32x4){0.f, 0.f, 0.f, 0.f};
        for (int ks = 0; ks < 6; ks++) {
            bf16x8 bfr[3];
            for (int i = 0; i < 3; i++) {
                int f = wn * 3 + i, c = f >> 2, j = f & 3;
                bfr[i] = *(const bf16x8*)&Wqf[
                    ((size_t)((c * 12 + p * 4 + j) * 6 + ks)) * 512 + lane * 8];
            }
            for (int mt = 0; mt < 2; mt++)
                for (int i = 0; i < 3; i++)
                    acc[mt][i] = __builtin_amdgcn_mfma_f32_16x16x32_bf16(
                        af[mt][ks], bfr[i], acc[mt][i], 0, 0, 0);
        }
        // B1: prev pass's attention/proj LDS reads done (p=0: af-hoist done)
        __syncthreads();
        // epilogue -> LDS. C/D layout: col = l15, row = quad*4 + r
        for (int i = 0; i < 3; i++) {
            int f = wn * 3 + i, c = f >> 2, j = f & 3;
            int cw = j * 16 + l15;                 // 0..63 within pass
            float bias = b_qkv[c * 192 + p * 64 + cw];
            int hl = cw >> 5, d = cw & 31;
            if (c < 2) {
                unsigned short* dst = (c == 0) ? lq2 : lk2;
                for (int mt = 0; mt < 2; mt++)
                    for (int r = 0; r < 4; r++) {
                        int t = wm * 32 + mt * 16 + quad * 4 + r;
                        dst[(hl * 64 + t) * 40 + d] = f2bf(acc[mt][i][r] + bias);
                    }
            } else {
                for (int mt = 0; mt < 2; mt++) {
                    union { unsigned short s[4]; uint2 u; } pk;
                    for (int r = 0; r < 4; r++)
                        pk.s[r] = f2bf(acc[mt][i][r] + bias);
                    int t0 = wm * 32 + mt * 16 + quad * 4;
                    *(uint2*)&lvt2[(hl * 32 + d) * 72 + t0] = pk.u;
                }
            }
        }
        __syncthreads();   // B2: Q/K/V^T visible to all waves

        // ---- attention: 8 tasks, exactly one per wave ----
        const int hl = wm;                 // local head 0..1
        const int mbase = wn * 16;         // query row tile
        const int hg = p * 2 + hl;         // global head

        float cmb[4][4];
        for (int j = 0; j < 4; j++)
            for (int r = 0; r < 4; r++)
                cmb[j][r] = combg[hg * 4096 + (mbase + quad * 4 + r) * 64 + j * 16 + l15];

        // S = Q K^T (d=32 = one k-step)
        bf16x8 aq = *(const bf16x8*)&lq2[(hl * 64 + mbase + l15) * 40 + quad * 8];
        f32x4 sacc[4];
        for (int j = 0; j < 4; j++) {
            bf16x8 bk = *(const bf16x8*)&lk2[(hl * 64 + j * 16 + l15) * 40 + quad * 8];
            f32x4 z = (f32x4){0.f, 0.f, 0.f, 0.f};
            sacc[j] = __builtin_amdgcn_mfma_f32_16x16x32_bf16(aq, bk, z, 0, 0, 0);
        }
        __syncthreads();   // B3: all lq2/lk2 reads done -> lsp overlay legal

        // softmax in registers; a row's 64 cols live in the 16-lane l15 group
        float pr[4][4], rsum[4];
        for (int r = 0; r < 4; r++) {
            float s0 = sacc[0][r] * SCALE + cmb[0][r];
            float s1 = sacc[1][r] * SCALE + cmb[1][r];
            float s2 = sacc[2][r] * SCALE + cmb[2][r];
            float s3 = sacc[3][r] * SCALE + cmb[3][r];
            float m = fmaxf(fmaxf(s0, s1), fmaxf(s2, s3));
            for (int o = 1; o < 16; o <<= 1) m = fmaxf(m, __shfl_xor(m, o, 64));
            pr[0][r] = __expf(s0 - m); pr[1][r] = __expf(s1 - m);
            pr[2][r] = __expf(s2 - m); pr[3][r] = __expf(s3 - m);
            float su = pr[0][r] + pr[1][r] + pr[2][r] + pr[3][r];
            for (int o = 1; o < 16; o <<= 1) su += __shfl_xor(su, o, 64);
            rsum[r] = su;
        }

        // P (unnormalized) -> wave-private scratch [16][72] (same-wave RAW)
        for (int j = 0; j < 4; j++)
            for (int r = 0; r < 4; r++)
                lspw[(quad * 4 + r) * 72 + j * 16 + l15] = f2bf(pr[j][r]);

        // O = P V^T  (K=64 -> 2 k-steps, 2 d-tiles)
        f32x4 oacc[2];
        oacc[0] = (f32x4){0.f, 0.f, 0.f, 0.f};
        oacc[1] = (f32x4){0.f, 0.f, 0.f, 0.f};
        for (int kstep = 0; kstep < 2; kstep++) {
            bf16x8 ap = *(const bf16x8*)&lspw[l15 * 72 + kstep * 32 + quad * 8];
            for (int n2 = 0; n2 < 2; n2++) {
                bf16x8 bv = *(const bf16x8*)&lvt2[
                    (hl * 32 + n2 * 16 + l15) * 72 + kstep * 32 + quad * 8];
                oacc[n2] = __builtin_amdgcn_mfma_f32_16x16x32_bf16(ap, bv, oacc[n2], 0, 0, 0);
            }
        }

        // normalize + write Xa slice (bf16): col = hl*32 + d (in-pass channel)
        for (int r = 0; r < 4; r++) {
            float inv = 1.0f / rsum[r];
            int t = mbase + quad * 4 + r;
            for (int n2 = 0; n2 < 2; n2++)
                lxa[t * 72 + hl * 32 + n2 * 16 + l15] = f2bf(oacc[n2][r] * inv);
        }
        __syncthreads();   // B4: lxa visible cross-wave

        // ---- proj partial: rank-64 update, k-slice [p*64, p*64+64) ----
        bf16x8 pf[2][2];
        for (int mt = 0; mt < 2; mt++)
            for (int kk = 0; kk < 2; kk++)
                pf[mt][kk] = *(const bf16x8*)&lxa[
                    (wm * 32 + mt * 16 + l15) * 72 + kk * 32 + quad * 8];
        for (int kk = 0; kk < 2; kk++) {
            bf16x8 bfr[3];
            for (int nt = 0; nt < 3; nt++)
                bfr[nt] = *(const bf16x8*)&Wpf[
                    ((size_t)((wn * 3 + nt) * 6 + (p * 2 + kk))) * 512 + lane * 8];
            for (int mt = 0; mt < 2; mt++)
                for (int nt = 0; nt < 3; nt++)
                    pacc[mt][nt] = __builtin_amdgcn_mfma_f32_16x16x32_bf16(
                        pf[mt][kk], bfr[nt], pacc[mt][nt], 0, 0, 0);
        }
        // next pass's B1 protects lq2/lk2/lvt2/lxa/lsp reuse
    }

    // ---- write out (fp32 + bias) ----
    for (int nt = 0; nt < 3; nt++) {
        int cw = wn * 48 + nt * 16 + l15;       // 0..191
        float bias = b_proj[cw];
        for (int mt = 0; mt < 2; mt++)
            for (int r = 0; r < 4; r++) {
                int t = wm * 32 + mt * 16 + quad * 4 + r;
                out[((size_t)bwin * 64 + t) * 192 + cw] = pacc[mt][nt][r] + bias;
            }
    }
}

// ---------------------------------------------------------------------------
extern "C" void kernel_launch(void* const* d_in, const int* in_sizes, int n_in,
                              void* d_out, int out_size, void* d_ws, size_t ws_size,
                              hipStream_t stream) {
    const float* x      = (const float*)d_in[0];
    const float* mask   = (const float*)d_in[1];
    const float* w_qkv  = (const float*)d_in[2];
    const float* b_qkv  = (const float*)d_in[3];
    const float* rpbt   = (const float*)d_in[4];
    const float* w_proj = (const float*)d_in[5];
    const float* b_proj = (const float*)d_in[6];
    float* out = (float*)d_out;

    const int B = in_sizes[0] / (NTOK * WDIM);   // 2048

    char* ws = (char*)d_ws;
    size_t o = 0;
    unsigned short* Wq = (unsigned short*)(ws + o); o += 576 * 192 * 2;
    unsigned short* Wp = (unsigned short*)(ws + o); o += 192 * 192 * 2;
    float* comb        = (float*)(ws + o);         o += (size_t)64 * NH * NTOK * NTOK * 4;

    const int prep_elems = 576 * 192 + 192 * 192 + 64 * NH * NTOK * NTOK;
    prep_kernel<<<(prep_elems + 255) / 256, 256, 0, stream>>>(
        w_qkv, w_proj, rpbt, mask, Wq, Wp, comb);
    fused_kernel<<<B, 512, 0, stream>>>(
        x, Wq, b_qkv, Wp, b_proj, comb, out);
}

// Round 5
// 298.517 us; speedup vs baseline: 1.5010x; 1.5010x over previous
//
#include <hip/hip_runtime.h>
#include <hip/hip_bf16.h>
#include <cstdint>

// ---------------------------------------------------------------------------
// WindowAttention, fully fused, static-LDS 38.9KB: B windows (2048), N=64,
// DIM=192, H=6 heads, d=32.
//   prep : weights -> bf16 MFMA-fragment-linear, comb = rel_bias + mask
//   fused: per-window block (512 thr, 8 waves). 3 passes over head-pairs:
//            pass p: QKV GEMM (A-frags in regs, B-frags from L2) for heads
//            {2p,2p+1} -> Q,K,V^T in LDS -> attention (1 task/wave, softmax
//            in regs) -> Xa slice in LDS -> rank-64 proj update into reg acc.
//          After 3 passes: write out fp32 + bias.
// LDS live-range overlays:
//   * lq2/lk2/lvt2/lxa alias the dead X-staging buffer (af hoisted to regs)
//   * P-scratch aliases lq2+lk2, legalized by a barrier after the QK^T MFMAs
// -> 38912 B/block -> 3 blocks/CU (VGPR-capped at 84), vs 2 at 64.5KB.
// __launch_bounds__(512, 2): rounds 3/4 A-B showed (512,6) forces VGPR 84->40
// and ~470MB of symmetric scratch spill traffic (329us); (512,2) is spill-free.
// ---------------------------------------------------------------------------

#define NTOK 64
#define NH 6
#define HD 32
#define WDIM 192
#define SCALE 0.17677669529663689f

typedef __bf16 bf16x8 __attribute__((ext_vector_type(8)));
typedef float f32x4 __attribute__((ext_vector_type(4)));

__device__ inline unsigned short f2bf(float f) {
    union { float f; unsigned u; } v; v.f = f;
    unsigned r = v.u + 0x7fff + ((v.u >> 16) & 1);   // RNE
    return (unsigned short)(r >> 16);
}

// ---------------------------------------------------------------------------
// K0: weight cast into MFMA B-fragment-linear order + combined bias table.
// Wfrag[((ntile*6 + ks)*64 + lane)*8 + j] = W[k][n], n = ntile*16+(lane&15),
// k = ks*32+(lane>>4)*8+j  -> a wave's B-fragment is one coalesced 1KB read.
// comb[w][h][r][c] = rpbt[relidx(r,c)][h] + mask[w][r][c]  (64*6*64*64 fp32)
// ---------------------------------------------------------------------------
__global__ __launch_bounds__(256) void prep_kernel(
    const float* __restrict__ w_qkv, const float* __restrict__ w_proj,
    const float* __restrict__ rpbt, const float* __restrict__ mask,
    unsigned short* __restrict__ wqkv_f, unsigned short* __restrict__ wproj_f,
    float* __restrict__ comb) {
    int idx = blockIdx.x * 256 + threadIdx.x;
    if (idx < 576 * 192) {
        int j = idx & 7, lane = (idx >> 3) & 63, t = idx >> 9;   // t = 0..215
        int ks = t % 6, ntile = t / 6;                           // ntile 0..35
        int n = ntile * 16 + (lane & 15);                        // 0..575
        int k = ks * 32 + (lane >> 4) * 8 + j;                   // 0..191
        wqkv_f[idx] = f2bf(w_qkv[k * 576 + n]);
        return;
    }
    int i2 = idx - 576 * 192;
    if (i2 < 192 * 192) {
        int j = i2 & 7, lane = (i2 >> 3) & 63, t = i2 >> 9;      // t = 0..71
        int ks = t % 6, ntile = t / 6;                           // ntile 0..11
        int n = ntile * 16 + (lane & 15);                        // 0..191
        int k = ks * 32 + (lane >> 4) * 8 + j;                   // 0..191
        wproj_f[i2] = f2bf(w_proj[k * 192 + n]);
        return;
    }
    int i3 = i2 - 192 * 192;
    if (i3 < 64 * NH * NTOK * NTOK) {
        int c = i3 & 63, r = (i3 >> 6) & 63;
        int h = (i3 >> 12) % NH;
        int w = i3 / (NH * 4096);
        int rr = (r >> 3) - (c >> 3) + 7;     // row-coord delta (0..14)
        int cc = (r & 7) - (c & 7) + 7;       // col-coord delta (0..14)
        comb[i3] = rpbt[(rr * 15 + cc) * NH + h] + mask[w * 4096 + r * 64 + c];
    }
}

// ---------------------------------------------------------------------------
// Fused per-window kernel. 512 threads = 8 waves: wm = wave>>2 (row half),
// wn = wave&3 (n-group). Static LDS: sm[19456] shorts = 38912 B.
//   phase 0 : lx  = sm[0..12800)            X bf16 [64][200]
//   overlay : lq2 = sm[0..5120)             Q pair [2][64][40]
//             lk2 = sm[5120..10240)         K pair [2][64][40]
//             lvt2= sm[10240..14848)        V^T    [2][32][72]
//             lxa = sm[14848..19456)        Xa slice [64][72]
//             lsp = sm[wave*1152..+1152)    P scratch (aliases lq2/lk2,
//                                           valid after barrier B3)
// Barriers/pass: B1 (pre-epilogue), B2 (post-epilogue), B3 (post-QK^T,
// legalizes lsp overlay), B4 (pre-proj, lxa cross-wave).
// ---------------------------------------------------------------------------
__global__ __launch_bounds__(512, 2) void fused_kernel(
    const float* __restrict__ X, const unsigned short* __restrict__ Wqf,
    const float* __restrict__ b_qkv, const unsigned short* __restrict__ Wpf,
    const float* __restrict__ b_proj, const float* __restrict__ comb,
    float* __restrict__ out) {
    __shared__ unsigned short sm[19456];
    unsigned short* lx   = sm;              // [64][200], dies at af-hoist
    unsigned short* lq2  = sm;              // [2][64][40]
    unsigned short* lk2  = sm + 5120;       // [2][64][40]
    unsigned short* lvt2 = sm + 10240;      // [2][32][72]
    unsigned short* lxa  = sm + 14848;      // [64][72]

    const int tid = threadIdx.x;
    const int bwin = blockIdx.x;
    const int wave = tid >> 6, lane = tid & 63;
    const int l15 = lane & 15, quad = lane >> 4;
    const int wm = wave >> 2, wn = wave & 3;

    // ---- stage X (64x192 fp32 -> bf16) ----
    const float4* xg = (const float4*)(X + (size_t)bwin * 64 * 192);
    for (int i = 0; i < 6; i++) {
        int e4 = tid + i * 512;            // 3072 float4
        int row = e4 / 48, c4 = e4 % 48;
        float4 v = xg[e4];
        union { unsigned short s[4]; uint2 u; } pk;
        pk.s[0] = f2bf(v.x); pk.s[1] = f2bf(v.y);
        pk.s[2] = f2bf(v.z); pk.s[3] = f2bf(v.w);
        *(uint2*)&lx[row * 200 + c4 * 4] = pk.u;
    }
    __syncthreads();

    // ---- hoist A-fragments (X rows wm*32..+32, all K) into registers ----
    bf16x8 af[2][6];
    for (int mt = 0; mt < 2; mt++)
        for (int ks = 0; ks < 6; ks++)
            af[mt][ks] = *(const bf16x8*)&lx[(wm * 32 + mt * 16 + l15) * 200 + ks * 32 + quad * 8];
    // lx dead from here (overlay becomes writable after B1 of pass 0)
    unsigned short* lspw = sm + wave * 1152;   // [16][72] per wave

    f32x4 pacc[2][3];                           // proj accumulator, all passes
    for (int mt = 0; mt < 2; mt++)
        for (int nt = 0; nt < 3; nt++)
            pacc[mt][nt] = (f32x4){0.f, 0.f, 0.f, 0.f};

    const float* combg = comb + ((size_t)(bwin & 63) * NH) * 4096;

    for (int p = 0; p < 3; p++) {
        // ---- QKV GEMM for head-pair p (regs + global only, no LDS) ----
        f32x4 acc[2][3];
        for (int mt = 0; mt < 2; mt++)
            for (int i = 0; i < 3; i++)
                acc[mt][i] = (f32x4){0.f, 0.f, 0.f, 0.f};
        for (int ks = 0; ks < 6; ks++) {
            bf16x8 bfr[3];
            for (int i = 0; i < 3; i++) {
                int f = wn * 3 + i, c = f >> 2, j = f & 3;
                bfr[i] = *(const bf16x8*)&Wqf[
                    ((size_t)((c * 12 + p * 4 + j) * 6 + ks)) * 512 + lane * 8];
            }
            for (int mt = 0; mt < 2; mt++)
                for (int i = 0; i < 3; i++)
                    acc[mt][i] = __builtin_amdgcn_mfma_f32_16x16x32_bf16(
                        af[mt][ks], bfr[i], acc[mt][i], 0, 0, 0);
        }
        // B1: prev pass's attention/proj LDS reads done (p=0: af-hoist done)
        __syncthreads();
        // epilogue -> LDS. C/D layout: col = l15, row = quad*4 + r
        for (int i = 0; i < 3; i++) {
            int f = wn * 3 + i, c = f >> 2, j = f & 3;
            int cw = j * 16 + l15;                 // 0..63 within pass
            float bias = b_qkv[c * 192 + p * 64 + cw];
            int hl = cw >> 5, d = cw & 31;
            if (c < 2) {
                unsigned short* dst = (c == 0) ? lq2 : lk2;
                for (int mt = 0; mt < 2; mt++)
                    for (int r = 0; r < 4; r++) {
                        int t = wm * 32 + mt * 16 + quad * 4 + r;
                        dst[(hl * 64 + t) * 40 + d] = f2bf(acc[mt][i][r] + bias);
                    }
            } else {
                for (int mt = 0; mt < 2; mt++) {
                    union { unsigned short s[4]; uint2 u; } pk;
                    for (int r = 0; r < 4; r++)
                        pk.s[r] = f2bf(acc[mt][i][r] + bias);
                    int t0 = wm * 32 + mt * 16 + quad * 4;
                    *(uint2*)&lvt2[(hl * 32 + d) * 72 + t0] = pk.u;
                }
            }
        }
        __syncthreads();   // B2: Q/K/V^T visible to all waves

        // ---- attention: 8 tasks, exactly one per wave ----
        const int hl = wm;                 // local head 0..1
        const int mbase = wn * 16;         // query row tile
        const int hg = p * 2 + hl;         // global head

        float cmb[4][4];
        for (int j = 0; j < 4; j++)
            for (int r = 0; r < 4; r++)
                cmb[j][r] = combg[hg * 4096 + (mbase + quad * 4 + r) * 64 + j * 16 + l15];

        // S = Q K^T (d=32 = one k-step)
        bf16x8 aq = *(const bf16x8*)&lq2[(hl * 64 + mbase + l15) * 40 + quad * 8];
        f32x4 sacc[4];
        for (int j = 0; j < 4; j++) {
            bf16x8 bk = *(const bf16x8*)&lk2[(hl * 64 + j * 16 + l15) * 40 + quad * 8];
            f32x4 z = (f32x4){0.f, 0.f, 0.f, 0.f};
            sacc[j] = __builtin_amdgcn_mfma_f32_16x16x32_bf16(aq, bk, z, 0, 0, 0);
        }
        __syncthreads();   // B3: all lq2/lk2 reads done -> lsp overlay legal

        // softmax in registers; a row's 64 cols live in the 16-lane l15 group
        float pr[4][4], rsum[4];
        for (int r = 0; r < 4; r++) {
            float s0 = sacc[0][r] * SCALE + cmb[0][r];
            float s1 = sacc[1][r] * SCALE + cmb[1][r];
            float s2 = sacc[2][r] * SCALE + cmb[2][r];
            float s3 = sacc[3][r] * SCALE + cmb[3][r];
            float m = fmaxf(fmaxf(s0, s1), fmaxf(s2, s3));
            for (int o = 1; o < 16; o <<= 1) m = fmaxf(m, __shfl_xor(m, o, 64));
            pr[0][r] = __expf(s0 - m); pr[1][r] = __expf(s1 - m);
            pr[2][r] = __expf(s2 - m); pr[3][r] = __expf(s3 - m);
            float su = pr[0][r] + pr[1][r] + pr[2][r] + pr[3][r];
            for (int o = 1; o < 16; o <<= 1) su += __shfl_xor(su, o, 64);
            rsum[r] = su;
        }

        // P (unnormalized) -> wave-private scratch [16][72] (same-wave RAW)
        for (int j = 0; j < 4; j++)
            for (int r = 0; r < 4; r++)
                lspw[(quad * 4 + r) * 72 + j * 16 + l15] = f2bf(pr[j][r]);

        // O = P V^T  (K=64 -> 2 k-steps, 2 d-tiles)
        f32x4 oacc[2];
        oacc[0] = (f32x4){0.f, 0.f, 0.f, 0.f};
        oacc[1] = (f32x4){0.f, 0.f, 0.f, 0.f};
        for (int kstep = 0; kstep < 2; kstep++) {
            bf16x8 ap = *(const bf16x8*)&lspw[l15 * 72 + kstep * 32 + quad * 8];
            for (int n2 = 0; n2 < 2; n2++) {
                bf16x8 bv = *(const bf16x8*)&lvt2[
                    (hl * 32 + n2 * 16 + l15) * 72 + kstep * 32 + quad * 8];
                oacc[n2] = __builtin_amdgcn_mfma_f32_16x16x32_bf16(ap, bv, oacc[n2], 0, 0, 0);
            }
        }

        // normalize + write Xa slice (bf16): col = hl*32 + d (in-pass channel)
        for (int r = 0; r < 4; r++) {
            float inv = 1.0f / rsum[r];
            int t = mbase + quad * 4 + r;
            for (int n2 = 0; n2 < 2; n2++)
                lxa[t * 72 + hl * 32 + n2 * 16 + l15] = f2bf(oacc[n2][r] * inv);
        }
        __syncthreads();   // B4: lxa visible cross-wave

        // ---- proj partial: rank-64 update, k-slice [p*64, p*64+64) ----
        bf16x8 pf[2][2];
        for (int mt = 0; mt < 2; mt++)
            for (int kk = 0; kk < 2; kk++)
                pf[mt][kk] = *(const bf16x8*)&lxa[
                    (wm * 32 + mt * 16 + l15) * 72 + kk * 32 + quad * 8];
        for (int kk = 0; kk < 2; kk++) {
            bf16x8 bfr[3];
            for (int nt = 0; nt < 3; nt++)
                bfr[nt] = *(const bf16x8*)&Wpf[
                    ((size_t)((wn * 3 + nt) * 6 + (p * 2 + kk))) * 512 + lane * 8];
            for (int mt = 0; mt < 2; mt++)
                for (int nt = 0; nt < 3; nt++)
                    pacc[mt][nt] = __builtin_amdgcn_mfma_f32_16x16x32_bf16(
                        pf[mt][kk], bfr[nt], pacc[mt][nt], 0, 0, 0);
        }
        // next pass's B1 protects lq2/lk2/lvt2/lxa/lsp reuse
    }

    // ---- write out (fp32 + bias) ----
    for (int nt = 0; nt < 3; nt++) {
        int cw = wn * 48 + nt * 16 + l15;       // 0..191
        float bias = b_proj[cw];
        for (int mt = 0; mt < 2; mt++)
            for (int r = 0; r < 4; r++) {
                int t = wm * 32 + mt * 16 + quad * 4 + r;
                out[((size_t)bwin * 64 + t) * 192 + cw] = pacc[mt][nt][r] + bias;
            }
    }
}

// ---------------------------------------------------------------------------
extern "C" void kernel_launch(void* const* d_in, const int* in_sizes, int n_in,
                              void* d_out, int out_size, void* d_ws, size_t ws_size,
                              hipStream_t stream) {
    const float* x      = (const float*)d_in[0];
    const float* mask   = (const float*)d_in[1];
    const float* w_qkv  = (const float*)d_in[2];
    const float* b_qkv  = (const float*)d_in[3];
    const float* rpbt   = (const float*)d_in[4];
    const float* w_proj = (const float*)d_in[5];
    const float* b_proj = (const float*)d_in[6];
    float* out = (float*)d_out;

    const int B = in_sizes[0] / (NTOK * WDIM);   // 2048

    char* ws = (char*)d_ws;
    size_t o = 0;
    unsigned short* Wq = (unsigned short*)(ws + o); o += 576 * 192 * 2;
    unsigned short* Wp = (unsigned short*)(ws + o); o += 192 * 192 * 2;
    float* comb        = (float*)(ws + o);         o += (size_t)64 * NH * NTOK * NTOK * 4;

    const int prep_elems = 576 * 192 + 192 * 192 + 64 * NH * NTOK * NTOK;
    prep_kernel<<<(prep_elems + 255) / 256, 256, 0, stream>>>(
        w_qkv, w_proj, rpbt, mask, Wq, Wp, comb);
    fused_kernel<<<B, 512, 0, stream>>>(
        x, Wq, b_qkv, Wp, b_proj, comb, out);
}

// Round 6
// 291.444 us; speedup vs baseline: 1.5374x; 1.0243x over previous
//
#include <hip/hip_runtime.h>
#include <hip/hip_bf16.h>
#include <cstdint>

// ---------------------------------------------------------------------------
// WindowAttention, fully fused: B windows (2048), N=64, DIM=192, H=6, d=32.
//   prep : weights -> bf16 MFMA-fragment-linear, comb = rel_bias + mask
//   fused: per-window block (512 thr, 8 waves). 3 passes over head-pairs:
//            QKV GEMM (A-frags in regs, B-frags double-buffered from L2)
//            -> Q,K,V^T in LDS -> attention (1 task/wave, softmax in regs)
//            -> Xa slice in LDS -> rank-64 proj update into reg acc.
// Round-6 levers (R3==R5 at 172us proved VGPR-slot-capped latency-bound):
//   * B-frag 2-deep pipeline in QKV loop (compiler allocated none at VGPR 84)
//   * cmb issued at pass start (hides under GEMM), proj-frags around B4
//   * lsp un-aliased -> barrier B3 deleted (3 barriers/pass, LDS 57.3KB --
//     harmless: VGPR caps residency at 2 blocks/CU, not LDS)
//   * native bf16 casts (1 VALU op vs 4)
// VGPR budget: must stay <=128 (slots step at 64/128/256; round-4 showed
// forcing <=64 spills catastrophically). Target ~110.
// ---------------------------------------------------------------------------

#define NTOK 64
#define NH 6
#define HD 32
#define WDIM 192
#define SCALE 0.17677669529663689f

typedef __bf16 bf16x8 __attribute__((ext_vector_type(8)));
typedef float f32x4 __attribute__((ext_vector_type(4)));

__device__ inline unsigned short f2bf(float f) {
    union { __bf16 b; unsigned short s; } u;
    u.b = (__bf16)f;                     // native RNE convert, single VALU op
    return u.s;
}

// ---------------------------------------------------------------------------
// K0: weight cast into MFMA B-fragment-linear order + combined bias table.
// Wfrag[((ntile*6 + ks)*64 + lane)*8 + j] = W[k][n], n = ntile*16+(lane&15),
// k = ks*32+(lane>>4)*8+j  -> a wave's B-fragment is one coalesced 1KB read.
// comb[w][h][r][c] = rpbt[relidx(r,c)][h] + mask[w][r][c]  (64*6*64*64 fp32)
// ---------------------------------------------------------------------------
__global__ __launch_bounds__(256) void prep_kernel(
    const float* __restrict__ w_qkv, const float* __restrict__ w_proj,
    const float* __restrict__ rpbt, const float* __restrict__ mask,
    unsigned short* __restrict__ wqkv_f, unsigned short* __restrict__ wproj_f,
    float* __restrict__ comb) {
    int idx = blockIdx.x * 256 + threadIdx.x;
    if (idx < 576 * 192) {
        int j = idx & 7, lane = (idx >> 3) & 63, t = idx >> 9;   // t = 0..215
        int ks = t % 6, ntile = t / 6;                           // ntile 0..35
        int n = ntile * 16 + (lane & 15);                        // 0..575
        int k = ks * 32 + (lane >> 4) * 8 + j;                   // 0..191
        wqkv_f[idx] = f2bf(w_qkv[k * 576 + n]);
        return;
    }
    int i2 = idx - 576 * 192;
    if (i2 < 192 * 192) {
        int j = i2 & 7, lane = (i2 >> 3) & 63, t = i2 >> 9;      // t = 0..71
        int ks = t % 6, ntile = t / 6;                           // ntile 0..11
        int n = ntile * 16 + (lane & 15);                        // 0..191
        int k = ks * 32 + (lane >> 4) * 8 + j;                   // 0..191
        wproj_f[i2] = f2bf(w_proj[k * 192 + n]);
        return;
    }
    int i3 = i2 - 192 * 192;
    if (i3 < 64 * NH * NTOK * NTOK) {
        int c = i3 & 63, r = (i3 >> 6) & 63;
        int h = (i3 >> 12) % NH;
        int w = i3 / (NH * 4096);
        int rr = (r >> 3) - (c >> 3) + 7;     // row-coord delta (0..14)
        int cc = (r & 7) - (c & 7) + 7;       // col-coord delta (0..14)
        comb[i3] = rpbt[(rr * 15 + cc) * NH + h] + mask[w * 4096 + r * 64 + c];
    }
}

// ---------------------------------------------------------------------------
// Fused per-window kernel. 512 threads = 8 waves: wm = wave>>2 (row half),
// wn = wave&3 (n-group). Static LDS: sm[28672] shorts = 57344 B.
//   phase 0 : lx  = sm[0..12800)            X bf16 [64][200]
//   overlay : lq2 = sm[0..5120)             Q pair [2][64][40]
//             lk2 = sm[5120..10240)         K pair [2][64][40]
//             lvt2= sm[10240..14848)        V^T    [2][32][72]
//             lxa = sm[14848..19456)        Xa slice [64][72]
//   separate: lsp = sm[19456 + wave*1152)   P scratch [16][72]/wave
//             (own region -> no post-QK^T barrier needed; same-wave RAW only)
// Barriers/pass: B1 (pre-epilogue), B2 (post-epilogue), B4 (pre-proj).
// ---------------------------------------------------------------------------
__global__ __launch_bounds__(512, 2) void fused_kernel(
    const float* __restrict__ X, const unsigned short* __restrict__ Wqf,
    const float* __restrict__ b_qkv, const unsigned short* __restrict__ Wpf,
    const float* __restrict__ b_proj, const float* __restrict__ comb,
    float* __restrict__ out) {
    __shared__ unsigned short sm[28672];
    unsigned short* lx   = sm;              // [64][200], dies at af-hoist
    unsigned short* lq2  = sm;              // [2][64][40]
    unsigned short* lk2  = sm + 5120;       // [2][64][40]
    unsigned short* lvt2 = sm + 10240;      // [2][32][72]
    unsigned short* lxa  = sm + 14848;      // [64][72]

    const int tid = threadIdx.x;
    const int bwin = blockIdx.x;
    const int wave = tid >> 6, lane = tid & 63;
    const int l15 = lane & 15, quad = lane >> 4;
    const int wm = wave >> 2, wn = wave & 3;

    // ---- stage X (64x192 fp32 -> bf16) ----
    const float4* xg = (const float4*)(X + (size_t)bwin * 64 * 192);
    for (int i = 0; i < 6; i++) {
        int e4 = tid + i * 512;            // 3072 float4
        int row = e4 / 48, c4 = e4 % 48;
        float4 v = xg[e4];
        union { unsigned short s[4]; uint2 u; } pk;
        pk.s[0] = f2bf(v.x); pk.s[1] = f2bf(v.y);
        pk.s[2] = f2bf(v.z); pk.s[3] = f2bf(v.w);
        *(uint2*)&lx[row * 200 + c4 * 4] = pk.u;
    }
    __syncthreads();

    // ---- hoist A-fragments (X rows wm*32..+32, all K) into registers ----
    bf16x8 af[2][6];
    for (int mt = 0; mt < 2; mt++)
        for (int ks = 0; ks < 6; ks++)
            af[mt][ks] = *(const bf16x8*)&lx[(wm * 32 + mt * 16 + l15) * 200 + ks * 32 + quad * 8];
    // lx dead from here (overlay becomes writable after B1 of pass 0)
    unsigned short* lspw = sm + 19456 + wave * 1152;   // [16][72] per wave

    f32x4 pacc[2][3];                           // proj accumulator, all passes
    for (int mt = 0; mt < 2; mt++)
        for (int nt = 0; nt < 3; nt++)
            pacc[mt][nt] = (f32x4){0.f, 0.f, 0.f, 0.f};

    const float* combg = comb + ((size_t)(bwin & 63) * NH) * 4096;

    for (int p = 0; p < 3; p++) {
        const int hl = wm;                 // this wave's attn head (local)
        const int mbase = wn * 16;         // this wave's attn query tile
        const int hg = p * 2 + hl;         // global head

        // issue comb loads now: ~400cy L2 latency hides under the QKV GEMM
        float cmb[4][4];
        #pragma unroll
        for (int j = 0; j < 4; j++)
            #pragma unroll
            for (int r = 0; r < 4; r++)
                cmb[j][r] = combg[hg * 4096 + (mbase + quad * 4 + r) * 64 + j * 16 + l15];

        // ---- QKV GEMM for head-pair p, B-frags 2-deep pipelined ----
        const unsigned short* wptr[3];
        #pragma unroll
        for (int i = 0; i < 3; i++) {
            int f = wn * 3 + i, c = f >> 2, j = f & 3;
            wptr[i] = Wqf + ((size_t)((c * 12 + p * 4 + j) * 6)) * 512 + lane * 8;
        }
        f32x4 acc[2][3];
        #pragma unroll
        for (int mt = 0; mt < 2; mt++)
            #pragma unroll
            for (int i = 0; i < 3; i++)
                acc[mt][i] = (f32x4){0.f, 0.f, 0.f, 0.f};

        bf16x8 bcur[3], bnxt[3];
        #pragma unroll
        for (int i = 0; i < 3; i++)
            bcur[i] = *(const bf16x8*)(wptr[i]);
        #pragma unroll
        for (int ks = 0; ks < 6; ks++) {
            if (ks < 5) {
                #pragma unroll
                for (int i = 0; i < 3; i++)
                    bnxt[i] = *(const bf16x8*)(wptr[i] + (ks + 1) * 512);
            }
            #pragma unroll
            for (int mt = 0; mt < 2; mt++)
                #pragma unroll
                for (int i = 0; i < 3; i++)
                    acc[mt][i] = __builtin_amdgcn_mfma_f32_16x16x32_bf16(
                        af[mt][ks], bcur[i], acc[mt][i], 0, 0, 0);
            #pragma unroll
            for (int i = 0; i < 3; i++)
                bcur[i] = bnxt[i];
        }
        // B1: prev pass's attention/proj LDS reads done (p=0: af-hoist done)
        __syncthreads();
        // epilogue -> LDS. C/D layout: col = l15, row = quad*4 + r
        #pragma unroll
        for (int i = 0; i < 3; i++) {
            int f = wn * 3 + i, c = f >> 2, j = f & 3;
            int cw = j * 16 + l15;                 // 0..63 within pass
            float bias = b_qkv[c * 192 + p * 64 + cw];
            int hle = cw >> 5, d = cw & 31;
            if (c < 2) {
                unsigned short* dst = (c == 0) ? lq2 : lk2;
                #pragma unroll
                for (int mt = 0; mt < 2; mt++)
                    #pragma unroll
                    for (int r = 0; r < 4; r++) {
                        int t = wm * 32 + mt * 16 + quad * 4 + r;
                        dst[(hle * 64 + t) * 40 + d] = f2bf(acc[mt][i][r] + bias);
                    }
            } else {
                #pragma unroll
                for (int mt = 0; mt < 2; mt++) {
                    union { unsigned short s[4]; uint2 u; } pk;
                    #pragma unroll
                    for (int r = 0; r < 4; r++)
                        pk.s[r] = f2bf(acc[mt][i][r] + bias);
                    int t0 = wm * 32 + mt * 16 + quad * 4;
                    *(uint2*)&lvt2[(hle * 32 + d) * 72 + t0] = pk.u;
                }
            }
        }
        __syncthreads();   // B2: Q/K/V^T visible to all waves

        // ---- attention: 8 tasks, exactly one per wave ----
        // S = Q K^T (d=32 = one k-step)
        bf16x8 aq = *(const bf16x8*)&lq2[(hl * 64 + mbase + l15) * 40 + quad * 8];
        f32x4 sacc[4];
        #pragma unroll
        for (int j = 0; j < 4; j++) {
            bf16x8 bk = *(const bf16x8*)&lk2[(hl * 64 + j * 16 + l15) * 40 + quad * 8];
            f32x4 z = (f32x4){0.f, 0.f, 0.f, 0.f};
            sacc[j] = __builtin_amdgcn_mfma_f32_16x16x32_bf16(aq, bk, z, 0, 0, 0);
        }

        // softmax in registers; a row's 64 cols live in the 16-lane l15 group
        float pr[4][4], rsum[4];
        #pragma unroll
        for (int r = 0; r < 4; r++) {
            float s0 = sacc[0][r] * SCALE + cmb[0][r];
            float s1 = sacc[1][r] * SCALE + cmb[1][r];
            float s2 = sacc[2][r] * SCALE + cmb[2][r];
            float s3 = sacc[3][r] * SCALE + cmb[3][r];
            float m = fmaxf(fmaxf(s0, s1), fmaxf(s2, s3));
            for (int o = 1; o < 16; o <<= 1) m = fmaxf(m, __shfl_xor(m, o, 64));
            pr[0][r] = __expf(s0 - m); pr[1][r] = __expf(s1 - m);
            pr[2][r] = __expf(s2 - m); pr[3][r] = __expf(s3 - m);
            float su = pr[0][r] + pr[1][r] + pr[2][r] + pr[3][r];
            for (int o = 1; o < 16; o <<= 1) su += __shfl_xor(su, o, 64);
            rsum[r] = su;
        }

        // P (unnormalized) -> wave-private scratch [16][72] (same-wave RAW,
        // dedicated region -> no barrier; compiler inserts lgkmcnt wait)
        #pragma unroll
        for (int j = 0; j < 4; j++)
            #pragma unroll
            for (int r = 0; r < 4; r++)
                lspw[(quad * 4 + r) * 72 + j * 16 + l15] = f2bf(pr[j][r]);

        // O = P V^T  (K=64 -> 2 k-steps, 2 d-tiles)
        f32x4 oacc[2];
        oacc[0] = (f32x4){0.f, 0.f, 0.f, 0.f};
        oacc[1] = (f32x4){0.f, 0.f, 0.f, 0.f};
        #pragma unroll
        for (int kstep = 0; kstep < 2; kstep++) {
            bf16x8 ap = *(const bf16x8*)&lspw[l15 * 72 + kstep * 32 + quad * 8];
            #pragma unroll
            for (int n2 = 0; n2 < 2; n2++) {
                bf16x8 bv = *(const bf16x8*)&lvt2[
                    (hl * 32 + n2 * 16 + l15) * 72 + kstep * 32 + quad * 8];
                oacc[n2] = __builtin_amdgcn_mfma_f32_16x16x32_bf16(ap, bv, oacc[n2], 0, 0, 0);
            }
        }

        // prefetch proj B-frags kk=0 (hide L2 latency under normalize + B4)
        bf16x8 pb0[3];
        #pragma unroll
        for (int nt = 0; nt < 3; nt++)
            pb0[nt] = *(const bf16x8*)&Wpf[
                ((size_t)((wn * 3 + nt) * 6 + (p * 2 + 0))) * 512 + lane * 8];

        // normalize + write Xa slice (bf16): col = hl*32 + d
        #pragma unroll
        for (int r = 0; r < 4; r++) {
            float inv = 1.0f / rsum[r];
            int t = mbase + quad * 4 + r;
            #pragma unroll
            for (int n2 = 0; n2 < 2; n2++)
                lxa[t * 72 + hl * 32 + n2 * 16 + l15] = f2bf(oacc[n2][r] * inv);
        }
        __syncthreads();   // B4: lxa visible cross-wave

        // ---- proj partial: rank-64 update, k-slice [p*64, p*64+64) ----
        bf16x8 pb1[3];
        #pragma unroll
        for (int nt = 0; nt < 3; nt++)
            pb1[nt] = *(const bf16x8*)&Wpf[
                ((size_t)((wn * 3 + nt) * 6 + (p * 2 + 1))) * 512 + lane * 8];
        bf16x8 pf[2][2];
        #pragma unroll
        for (int mt = 0; mt < 2; mt++)
            #pragma unroll
            for (int kk = 0; kk < 2; kk++)
                pf[mt][kk] = *(const bf16x8*)&lxa[
                    (wm * 32 + mt * 16 + l15) * 72 + kk * 32 + quad * 8];
        #pragma unroll
        for (int mt = 0; mt < 2; mt++)
            #pragma unroll
            for (int nt = 0; nt < 3; nt++)
                pacc[mt][nt] = __builtin_amdgcn_mfma_f32_16x16x32_bf16(
                    pf[mt][0], pb0[nt], pacc[mt][nt], 0, 0, 0);
        #pragma unroll
        for (int mt = 0; mt < 2; mt++)
            #pragma unroll
            for (int nt = 0; nt < 3; nt++)
                pacc[mt][nt] = __builtin_amdgcn_mfma_f32_16x16x32_bf16(
                    pf[mt][1], pb1[nt], pacc[mt][nt], 0, 0, 0);
        // next pass's B1 protects lq2/lk2/lvt2/lxa reuse
    }

    // ---- write out (fp32 + bias) ----
    for (int nt = 0; nt < 3; nt++) {
        int cw = wn * 48 + nt * 16 + l15;       // 0..191
        float bias = b_proj[cw];
        for (int mt = 0; mt < 2; mt++)
            for (int r = 0; r < 4; r++) {
                int t = wm * 32 + mt * 16 + quad * 4 + r;
                out[((size_t)bwin * 64 + t) * 192 + cw] = pacc[mt][nt][r] + bias;
            }
    }
}

// ---------------------------------------------------------------------------
extern "C" void kernel_launch(void* const* d_in, const int* in_sizes, int n_in,
                              void* d_out, int out_size, void* d_ws, size_t ws_size,
                              hipStream_t stream) {
    const float* x      = (const float*)d_in[0];
    const float* mask   = (const float*)d_in[1];
    const float* w_qkv  = (const float*)d_in[2];
    const float* b_qkv  = (const float*)d_in[3];
    const float* rpbt   = (const float*)d_in[4];
    const float* w_proj = (const float*)d_in[5];
    const float* b_proj = (const float*)d_in[6];
    float* out = (float*)d_out;

    const int B = in_sizes[0] / (NTOK * WDIM);   // 2048

    char* ws = (char*)d_ws;
    size_t o = 0;
    unsigned short* Wq = (unsigned short*)(ws + o); o += 576 * 192 * 2;
    unsigned short* Wp = (unsigned short*)(ws + o); o += 192 * 192 * 2;
    float* comb        = (float*)(ws + o);         o += (size_t)64 * NH * NTOK * NTOK * 4;

    const int prep_elems = 576 * 192 + 192 * 192 + 64 * NH * NTOK * NTOK;
    prep_kernel<<<(prep_elems + 255) / 256, 256, 0, stream>>>(
        w_qkv, w_proj, rpbt, mask, Wq, Wp, comb);
    fused_kernel<<<B, 512, 0, stream>>>(
        x, Wq, b_qkv, Wp, b_proj, comb, out);
}